// Round 8
// baseline (462.579 us; speedup 1.0000x reference)
//
#include <hip/hip_runtime.h>
#include <math.h>

// ---------------------------------------------------------------------------
// LinSinkhornPRModel: sigmoid(dist2 - dist1) of two Sinkhorn divergences.
//   - f_aa self-term cancels in dist2-dist1 -> C_xx never built.
//   - R7: fp16 C, two-pass row LSE (446us). Post-mortem: cost kernel latency-
//     bound (2 waves/SIMD, 90% idle MFMA pipe); rounds stall on LDS col-merge
//     + split-width partials.
//   - R8: round kernel thread-owns-columns (full-width tile, private col
//     accums, f/gb finalized in-kernel, 1 barrier); cost kernel 32-AGPR wave
//     tile + LDS-staged coalesced epilogue.
// ---------------------------------------------------------------------------

typedef __attribute__((ext_vector_type(8))) short short8;
typedef __attribute__((ext_vector_type(4))) float f32x4;
typedef __attribute__((ext_vector_type(8))) unsigned short u16x8;
typedef __attribute__((ext_vector_type(4))) unsigned short u16x4;

#define LOG2E 1.4426950408889634
#define LN2   0.6931471805599453

__device__ __forceinline__ float exp2fast(float x){
#if __has_builtin(__builtin_amdgcn_exp2f)
    return __builtin_amdgcn_exp2f(x);
#else
    return exp2f(x);
#endif
}
__device__ __forceinline__ void lse2_upd(float& m, float& s, float v){
    float M2 = fmaxf(m, v);
    s = s * exp2fast(m - M2) + exp2fast(v - M2);
    m = M2;
}
__device__ __forceinline__ void lse2_merge(float& m, float& s, float mo, float so){
    float M2 = fmaxf(m, mo);
    s = s * exp2fast(m - M2) + so * exp2fast(mo - M2);
    m = M2;
}
__device__ __forceinline__ unsigned short f2bf(float x){
    unsigned u = __float_as_uint(x);
    unsigned r = u + 0x7fffu + ((u >> 16) & 1u);
    return (unsigned short)(r >> 16);
}
__device__ __forceinline__ float bf2f(unsigned short h){
    return __uint_as_float(((unsigned)h) << 16);
}
__device__ __forceinline__ float h2f(unsigned short u){
    _Float16 h; __builtin_memcpy(&h, &u, 2); return (float)h;
}
__device__ __forceinline__ unsigned short f2h(float f){
    _Float16 h = (_Float16)f; unsigned short u; __builtin_memcpy(&u, &h, 2); return u;
}

// ----------------------------- setup kernels -------------------------------

__global__ void k_transposeW(const float* __restrict__ W, float* __restrict__ WT){
    int b = blockIdx.x, t = threadIdx.x;   // WT[k][o] = W[o][k]
    WT[b * 128 + t] = W[t * 128 + b];
}

__global__ __launch_bounds__(128)
void k_transform_all(const float* __restrict__ d, const float* __restrict__ si,
                     const float* __restrict__ sj, const float* __restrict__ WT,
                     unsigned short* __restrict__ th, unsigned short* __restrict__ tl,
                     float* __restrict__ hn)
{
    __shared__ float xs[8][128];
    __shared__ float red[16];
    const int t = threadIdx.x;
    const int r0 = blockIdx.x * 8;
    const float* src; int sr;
    if (r0 < 4096)      { src = d;  sr = r0; }
    else if (r0 < 6144) { src = si; sr = r0 - 4096; }
    else                { src = sj; sr = r0 - 6144; }
    for (int rr = 0; rr < 8; ++rr)
        xs[rr][t] = src[(size_t)(sr + rr) * 128 + t];
    __syncthreads();
    float acc[8];
#pragma unroll
    for (int rr = 0; rr < 8; ++rr) acc[rr] = 0.f;
    for (int k = 0; k < 128; ++k) {
        float wv = WT[k * 128 + t];
#pragma unroll
        for (int rr = 0; rr < 8; ++rr) acc[rr] = fmaf(xs[rr][k], wv, acc[rr]);
    }
#pragma unroll
    for (int rr = 0; rr < 8; ++rr) {
        float a = acc[rr];
        unsigned short hb = f2bf(a);
        th[(size_t)(r0 + rr) * 128 + t] = hb;
        tl[(size_t)(r0 + rr) * 128 + t] = f2bf(a - bf2f(hb));
        float sq = a * a;
#pragma unroll
        for (int o = 1; o < 64; o <<= 1) sq += __shfl_xor(sq, o);
        if ((t & 63) == 0) red[(t >> 6) * 8 + rr] = sq;
    }
    __syncthreads();
    if (t < 8) hn[r0 + t] = 0.5f * (red[t] + red[8 + t]);
}

__global__ void k_log_all(const float* __restrict__ h, const float* __restrict__ hi,
                          const float* __restrict__ hj, float* __restrict__ lg)
{
    int i = blockIdx.x * 256 + threadIdx.x;   // 8192 total
    float x;
    if (i < 4096)      x = h[i];
    else if (i < 6144) x = hi[i - 4096];
    else               x = hj[i - 6144];
    lg[i] = __log2f(x);
}

// ------------------------------ cost GEMM (MFMA) ---------------------------
// C[i][j] = max(hna[i]+hnb[j]-dot, 0) fp16; dot = hh+hl+lh (bf16 split).
// Block tile 64 rows x 128 cols; wave = 32x64 (acc 2x4 = 32 AGPR for
// occupancy). Swapped mfma -> C^T frag. Epilogue staged through LDS for
// 64B-per-row coalesced global stores.
struct CostPair {
    const unsigned short *Ah, *Al, *Bh, *Bl;
    const float *hna, *hnb;
    unsigned short* C; int ldc; int nty;
};
struct CostQuad { CostPair p[4]; };

#define CPAD 140

__global__ __launch_bounds__(256)
void k_cost_mfma(CostQuad Q)
{
    CostPair P = Q.p[blockIdx.z];
    if ((int)blockIdx.y >= P.nty) return;
    const int i0 = blockIdx.y * 64, j0 = blockIdx.x * 128;
    const int w = threadIdx.x >> 6, lane = threadIdx.x & 63;
    const int rh = w >> 1, ch = w & 1;
    const int ar = i0 + rh * 32;          // 32 rows via fi*16+lrow
    const int bc = j0 + ch * 64;          // 64 cols via fj*16+lrow
    const int lrow = lane & 15;
    const int kgrp = (lane >> 4) * 8;

    __shared__ unsigned short lds_c[64][CPAD];

    f32x4 acc[2][4];
#pragma unroll
    for (int a = 0; a < 2; ++a)
#pragma unroll
        for (int c = 0; c < 4; ++c) acc[a][c] = (f32x4){0.f, 0.f, 0.f, 0.f};

#pragma unroll
    for (int kc = 0; kc < 128; kc += 32) {
        short8 ah[2], al[2], bh[4], bl[4];
#pragma unroll
        for (int f = 0; f < 2; ++f) {
            size_t aoff = (size_t)(ar + f * 16 + lrow) * 128 + kc + kgrp;
            ah[f] = *reinterpret_cast<const short8*>(P.Ah + aoff);
            al[f] = *reinterpret_cast<const short8*>(P.Al + aoff);
        }
#pragma unroll
        for (int f = 0; f < 4; ++f) {
            size_t boff = (size_t)(bc + f * 16 + lrow) * 128 + kc + kgrp;
            bh[f] = *reinterpret_cast<const short8*>(P.Bh + boff);
            bl[f] = *reinterpret_cast<const short8*>(P.Bl + boff);
        }
#pragma unroll
        for (int fi = 0; fi < 2; ++fi)
#pragma unroll
            for (int fj = 0; fj < 4; ++fj) {
                acc[fi][fj] = __builtin_amdgcn_mfma_f32_16x16x32_bf16(bh[fj], ah[fi], acc[fi][fj], 0, 0, 0);
                acc[fi][fj] = __builtin_amdgcn_mfma_f32_16x16x32_bf16(bl[fj], ah[fi], acc[fi][fj], 0, 0, 0);
                acc[fi][fj] = __builtin_amdgcn_mfma_f32_16x16x32_bf16(bh[fj], al[fi], acc[fi][fj], 0, 0, 0);
            }
    }
    // C^T frag: C-row = lane&15, C-col = (lane>>4)*4 + e  -> stage into LDS
    const int rloc = lane & 15, cloc = (lane >> 4) * 4;
#pragma unroll
    for (int fi = 0; fi < 2; ++fi) {
        int lr = rh * 32 + fi * 16 + rloc;
        float ha = P.hna[i0 + lr];
#pragma unroll
        for (int fj = 0; fj < 4; ++fj) {
            int lc = ch * 64 + fj * 16 + cloc;
            f32x4 hb = *reinterpret_cast<const f32x4*>(P.hnb + j0 + lc);
            u16x4 v;
#pragma unroll
            for (int e = 0; e < 4; ++e)
                v[e] = f2h(fmaxf(ha + hb[e] - acc[fi][fj][e], 0.f));
            *reinterpret_cast<u16x4*>(&lds_c[lr][lc]) = v;
        }
    }
    __syncthreads();
    // coalesced store: thread t -> row t>>2, 32-col quarter t&3
    {
        const int row = threadIdx.x >> 2, q = threadIdx.x & 3;
        const unsigned short* srcp = &lds_c[row][q * 32];
        unsigned short* dstp = P.C + (size_t)(i0 + row) * P.ldc + j0 + q * 32;
#pragma unroll
        for (int k = 0; k < 4; ++k)
            *reinterpret_cast<u16x8*>(dstp + 8 * k) =
                *reinterpret_cast<const u16x8*>(srcp + 8 * k);
    }
}

// ------------------------------ round kernel -------------------------------
// Full-width tile: 16 rows x 2048 cols, thread t owns cols [8t, 8t+8).
// Row LSE: per-thread two-pass over 8 elems -> (m,s) per row in regs ->
// one LDS reduce (16 groups of 16) -> f/gb finalized in-kernel.
// Col LSE (dual only): thread-private online accums -> pm/ps partials.

struct R4Task {      // dual xy: C is [4096][2048]
    const unsigned short* C;
    const float* WB; const float* WA;
    const float* fold; const float* la;
    float* fout; float* fwout;
    float* pm; float* ps;            // [256][2048]
    int blk0;
};
struct R4YTask {     // yy row-only: C is [2048][2048]
    const unsigned short* C; const float* Wv;
    const float* fold; const float* logself;
    float* vout; float* wout;
    int blk0;
};
struct R4Args {
    R4Task d[2]; R4YTask y[2];
    float ie2, epsln2, ie2n, alpha, beta;
    int yblk0;
};

__global__ __launch_bounds__(256)
void k_round4(R4Args A)
{
    __shared__ float lmS[16][256];
    __shared__ float lsS[16][256];
    const int b = blockIdx.x;
    const int tid = threadIdx.x;
    const float nie2 = -A.ie2;
    const int c0 = tid * 8;

    float mrow[16], srow[16];

    if (b >= A.yblk0) {
        // ---- yy row-only tile ----
        R4YTask T = (b >= A.y[1].blk0) ? A.y[1] : A.y[0];
        const int chunk = b - T.blk0;
        const int row0 = chunk * 16;
        float wb[8];
#pragma unroll
        for (int e = 0; e < 8; ++e) wb[e] = T.Wv[c0 + e];
#pragma unroll 4
        for (int r = 0; r < 16; ++r) {
            u16x8 c = *reinterpret_cast<const u16x8*>(T.C + (size_t)(row0 + r) * 2048 + c0);
            float v[8];
#pragma unroll
            for (int e = 0; e < 8; ++e) v[e] = fmaf(h2f(c[e]), nie2, wb[e]);
            float M8 = fmaxf(fmaxf(fmaxf(v[0], v[1]), fmaxf(v[2], v[3])),
                             fmaxf(fmaxf(v[4], v[5]), fmaxf(v[6], v[7])));
            float s8 = 0.f;
#pragma unroll
            for (int e = 0; e < 8; ++e) s8 += exp2fast(v[e] - M8);
            mrow[r] = M8; srow[r] = s8;
        }
#pragma unroll
        for (int r = 0; r < 16; ++r) { lmS[r][tid] = mrow[r]; lsS[r][tid] = srow[r]; }
        __syncthreads();
        {
            const int row = tid >> 4, g = tid & 15;
            float m = lmS[row][g], s = lsS[row][g];
#pragma unroll
            for (int k = 1; k < 16; ++k)
                lse2_merge(m, s, lmS[row][g + 16 * k], lsS[row][g + 16 * k]);
#pragma unroll
            for (int o = 1; o < 16; o <<= 1) {
                float mo = __shfl_xor(m, o), so = __shfl_xor(s, o);
                lse2_merge(m, s, mo, so);
            }
            if (g == 0) {
                int rr = row0 + row;
                float val  = -A.epsln2 * (m + __log2f(s));
                float vnew = A.alpha * T.fold[rr] + A.beta * val;
                T.vout[rr] = vnew;
                T.wout[rr] = fmaf(vnew, A.ie2n, T.logself[rr]);
            }
        }
        return;
    }

    // ---- dual xy tile ----
    R4Task T = (b >= A.d[1].blk0) ? A.d[1] : A.d[0];
    const int chunk = b - T.blk0;
    const int row0 = chunk * 16;
    float wb[8];
#pragma unroll
    for (int e = 0; e < 8; ++e) wb[e] = T.WB[c0 + e];
    float mcol[8], scol[8];
#pragma unroll
    for (int e = 0; e < 8; ++e) { mcol[e] = -INFINITY; scol[e] = 0.f; }

#pragma unroll 4
    for (int r = 0; r < 16; ++r) {
        const float wa = T.WA[row0 + r];
        u16x8 c = *reinterpret_cast<const u16x8*>(T.C + (size_t)(row0 + r) * 2048 + c0);
        float u[8], v[8];
#pragma unroll
        for (int e = 0; e < 8; ++e) { u[e] = h2f(c[e]) * nie2; v[e] = u[e] + wb[e]; }
        float M8 = fmaxf(fmaxf(fmaxf(v[0], v[1]), fmaxf(v[2], v[3])),
                         fmaxf(fmaxf(v[4], v[5]), fmaxf(v[6], v[7])));
        float s8 = 0.f;
#pragma unroll
        for (int e = 0; e < 8; ++e) s8 += exp2fast(v[e] - M8);
        mrow[r] = M8; srow[r] = s8;
#pragma unroll
        for (int e = 0; e < 8; ++e) lse2_upd(mcol[e], scol[e], u[e] + wa);
    }
    // col partials (thread-private -> direct coalesced store)
    {
        size_t po = (size_t)chunk * 2048 + c0;
        f32x4 a0 = { mcol[0], mcol[1], mcol[2], mcol[3] };
        f32x4 a1 = { mcol[4], mcol[5], mcol[6], mcol[7] };
        f32x4 b0 = { scol[0], scol[1], scol[2], scol[3] };
        f32x4 b1 = { scol[4], scol[5], scol[6], scol[7] };
        *reinterpret_cast<f32x4*>(T.pm + po)     = a0;
        *reinterpret_cast<f32x4*>(T.pm + po + 4) = a1;
        *reinterpret_cast<f32x4*>(T.ps + po)     = b0;
        *reinterpret_cast<f32x4*>(T.ps + po + 4) = b1;
    }
    // row reduce + f finalize
#pragma unroll
    for (int r = 0; r < 16; ++r) { lmS[r][tid] = mrow[r]; lsS[r][tid] = srow[r]; }
    __syncthreads();
    {
        const int row = tid >> 4, g = tid & 15;
        float m = lmS[row][g], s = lsS[row][g];
#pragma unroll
        for (int k = 1; k < 16; ++k)
            lse2_merge(m, s, lmS[row][g + 16 * k], lsS[row][g + 16 * k]);
#pragma unroll
        for (int o = 1; o < 16; o <<= 1) {
            float mo = __shfl_xor(m, o), so = __shfl_xor(s, o);
            lse2_merge(m, s, mo, so);
        }
        if (g == 0) {
            int rr = row0 + row;
            float val  = -A.epsln2 * (m + __log2f(s));
            float vnew = A.alpha * T.fold[rr] + A.beta * val;
            T.fout[rr] = vnew;
            T.fwout[rr] = fmaf(vnew, A.ie2n, T.la[rr]);
        }
    }
}

// ------------------------------ combine kernel -----------------------------
// Column combine only: merge 256 row-chunk partials per column -> g update.
struct CombA { const float* pm; const float* ps; const float* gold;
               const float* lb; float* gout; float* gwout; };
struct C3Args { CombA a[2]; float epsln2, ie2n, alpha, beta; };

__global__ __launch_bounds__(256)
void k_comb3(C3Args A)
{
    const int b = blockIdx.x;             // 128 blocks: 64 per task
    const int tid = threadIdx.x;
    const int lane = tid & 63, w = tid >> 6;
    CombA T = A.a[b >> 6];
    const int bb = b & 63;
    const int jl = tid & 31, cg = tid >> 5;      // 8 chunk groups
    const int j = bb * 32 + jl;
    float m = -INFINITY, s = 0.f;
    for (int c = cg; c < 256; c += 8)
        lse2_merge(m, s, T.pm[(size_t)c * 2048 + j], T.ps[(size_t)c * 2048 + j]);
    {
        float mo = __shfl_xor(m, 32), so = __shfl_xor(s, 32);
        lse2_merge(m, s, mo, so);
    }
    __shared__ float smm[4][32], sss[4][32];
    if (lane < 32) { smm[w][lane] = m; sss[w][lane] = s; }
    __syncthreads();
    if (tid < 32) {
        m = smm[0][tid]; s = sss[0][tid];
        for (int q = 1; q < 4; ++q) lse2_merge(m, s, smm[q][tid], sss[q][tid]);
        float val = -A.epsln2 * (m + __log2f(s));
        float gnew = A.alpha * T.gold[j] + A.beta * val;
        T.gout[j] = gnew;
        T.gwout[j] = fmaf(gnew, A.ie2n, T.lb[j]);
    }
}

// ------------------------------ final reduce -------------------------------
__global__ __launch_bounds__(1024)
void k_final(const float* __restrict__ h, const float* __restrict__ hi,
             const float* __restrict__ hj,
             const float* __restrict__ f1f, const float* __restrict__ f2f,
             const float* __restrict__ g1f, const float* __restrict__ gb1f,
             const float* __restrict__ g2f, const float* __restrict__ gb2f,
             int N, int M, float* __restrict__ out)
{
    float acc = 0.f;
    for (int i = threadIdx.x; i < N; i += 1024)
        acc += h[i] * (f2f[i] - f1f[i]);
    for (int j = threadIdx.x; j < M; j += 1024)
        acc += hj[j] * (g2f[j] - gb2f[j]) - hi[j] * (g1f[j] - gb1f[j]);
#pragma unroll
    for (int o = 32; o; o >>= 1) acc += __shfl_xor(acc, o);
    __shared__ float red[16];
    const int lane = threadIdx.x & 63, w = threadIdx.x >> 6;
    if (lane == 0) red[w] = acc;
    __syncthreads();
    if (threadIdx.x == 0) {
        float t = 0.f;
        for (int q = 0; q < 16; ++q) t += red[q];
        out[0] = 1.f / (1.f + expf(-t));   // SCALING_FACTOR = 1
    }
}

// ------------------------------ orchestration ------------------------------

extern "C" void kernel_launch(void* const* d_in, const int* in_sizes, int n_in,
                              void* d_out, int out_size, void* d_ws, size_t ws_size,
                              hipStream_t stream)
{
    const float* d  = (const float*)d_in[0];
    const float* si = (const float*)d_in[1];
    const float* sj = (const float*)d_in[2];
    const float* h  = (const float*)d_in[3];
    const float* hi = (const float*)d_in[4];
    const float* hj = (const float*)d_in[5];
    const float* W  = (const float*)d_in[6];
    float* out = (float*)d_out;

    const int N = 4096, M = 2048;
    (void)in_sizes; (void)n_in; (void)out_size; (void)ws_size;

    float* ws = (float*)d_ws;
    size_t off = 0;
    auto alloc = [&](size_t n) { float* p = ws + off; off += (n + 63) & ~(size_t)63; return p; };

    float* WT    = alloc(128 * 128);
    float* lg2   = alloc(8192);
    float* hnAll = alloc(8192);
    unsigned short* thAll = (unsigned short*)alloc(8192 * 128 / 2);
    unsigned short* tlAll = (unsigned short*)alloc(8192 * 128 / 2);
    float* f1[2]  = { alloc(N), alloc(N) };
    float* f2[2]  = { alloc(N), alloc(N) };
    float* g1[2]  = { alloc(M), alloc(M) };
    float* g2[2]  = { alloc(M), alloc(M) };
    float* gb1[2] = { alloc(M), alloc(M) };
    float* gb2[2] = { alloc(M), alloc(M) };
    float* WA1[2] = { alloc(N), alloc(N) };
    float* WA2[2] = { alloc(N), alloc(N) };
    float* WB1[2] = { alloc(M), alloc(M) };
    float* WB2[2] = { alloc(M), alloc(M) };
    float* WY1[2] = { alloc(M), alloc(M) };
    float* WY2[2] = { alloc(M), alloc(M) };
    float* f1f = alloc(N); float* f2f = alloc(N);
    float* g1f = alloc(M); float* g2f = alloc(M);
    float* gb1f = alloc(M); float* gb2f = alloc(M);
    unsigned short* C1  = (unsigned short*)alloc((size_t)N * M / 2);
    unsigned short* C2  = (unsigned short*)alloc((size_t)N * M / 2);
    unsigned short* Cy1 = (unsigned short*)alloc((size_t)M * M / 2);
    unsigned short* Cy2 = (unsigned short*)alloc((size_t)M * M / 2);
    float* pm1 = alloc((size_t)256 * 2048);
    float* ps1 = alloc((size_t)256 * 2048);
    float* pm2 = alloc((size_t)256 * 2048);
    float* ps2 = alloc((size_t)256 * 2048);

    float* la2  = lg2;
    float* lbi2 = lg2 + 4096;
    float* lbj2 = lg2 + 6144;
    const float* hnx = hnAll;
    const float* hni = hnAll + 4096;
    const float* hnj = hnAll + 6144;
    const unsigned short* tdh  = thAll;
    const unsigned short* tdl  = tlAll;
    const unsigned short* tsih = thAll + (size_t)4096 * 128;
    const unsigned short* tsil = tlAll + (size_t)4096 * 128;
    const unsigned short* tsjh = thAll + (size_t)6144 * 128;
    const unsigned short* tsjl = tlAll + (size_t)6144 * 128;

    // ---- setup ----
    k_transposeW<<<128, 128, 0, stream>>>(W, WT);
    k_transform_all<<<1024, 128, 0, stream>>>(d, si, sj, WT, thAll, tlAll, hnAll);
    k_log_all<<<32, 256, 0, stream>>>(h, hi, hj, lg2);

    // ---- cost matrices: 4 GEMMs in one launch (64x128 block tiles) ----
    CostQuad Q;
    Q.p[0] = { tdh,  tdl,  tsih, tsil, hnx, hni, C1,  M, 64 };
    Q.p[1] = { tdh,  tdl,  tsjh, tsjl, hnx, hnj, C2,  M, 64 };
    Q.p[2] = { tsih, tsil, tsih, tsil, hni, hni, Cy1, M, 32 };
    Q.p[3] = { tsjh, tsjl, tsjh, tsjl, hnj, hnj, Cy2, M, 32 };
    k_cost_mfma<<<dim3(M / 128, N / 64, 4), 256, 0, stream>>>(Q);

    // ---- eps schedule ----
    double epsl[16]; int ne = 0;
    for (double sg = 32.0; sg > 0.05; sg *= 0.5) epsl[ne++] = sg * sg;
    epsl[ne++] = 0.05 * 0.05;   // ne == 11

    for (int r = 0; r <= ne + 1; ++r) {
        const bool init = (r == 0), fin = (r == ne + 1);
        const double eps  = init ? epsl[0] : (fin ? epsl[ne - 1] : epsl[r - 1]);
        const double epsn = (r + 1 <= ne) ? epsl[r] : epsl[ne - 1];
        const int in = init ? 0 : (r - 1) & 1;
        const int o  = r & 1;

        R4Args RA;
        RA.ie2    = (float)(LOG2E / eps);
        RA.epsln2 = (float)(eps * LN2);
        RA.ie2n   = (float)(LOG2E / epsn);
        RA.alpha  = (init || fin) ? 0.0f : 0.5f;
        RA.beta   = (init || fin) ? 1.0f : 0.5f;
        RA.yblk0  = 512;
        RA.d[0] = { C1, init ? lbi2 : WB1[in], init ? la2 : WA1[in], f1[in], la2,
                    fin ? f1f : f1[o], WA1[o], pm1, ps1, 0 };
        RA.d[1] = { C2, init ? lbj2 : WB2[in], init ? la2 : WA2[in], f2[in], la2,
                    fin ? f2f : f2[o], WA2[o], pm2, ps2, 256 };
        RA.y[0] = { Cy1, init ? lbi2 : WY1[in], gb1[in], lbi2,
                    fin ? gb1f : gb1[o], WY1[o], 512 };
        RA.y[1] = { Cy2, init ? lbj2 : WY2[in], gb2[in], lbj2,
                    fin ? gb2f : gb2[o], WY2[o], 640 };
        k_round4<<<768, 256, 0, stream>>>(RA);

        C3Args CA;
        CA.epsln2 = (float)(eps * LN2);
        CA.ie2n   = (float)(LOG2E / epsn);
        CA.alpha  = RA.alpha;
        CA.beta   = RA.beta;
        CA.a[0] = { pm1, ps1, g1[in], lbi2, fin ? g1f : g1[o], WB1[o] };
        CA.a[1] = { pm2, ps2, g2[in], lbj2, fin ? g2f : g2[o], WB2[o] };
        k_comb3<<<128, 256, 0, stream>>>(CA);
    }

    k_final<<<1, 1024, 0, stream>>>(h, hi, hj, f1f, f2f, g1f, gb1f, g2f, gb2f, N, M, out);
}

// Round 9
// 417.815 us; speedup vs baseline: 1.1071x; 1.1071x over previous
//
#include <hip/hip_runtime.h>
#include <math.h>

// ---------------------------------------------------------------------------
// LinSinkhornPRModel: sigmoid(dist2 - dist1) of two Sinkhorn divergences.
//   - f_aa self-term cancels in dist2-dist1 -> C_xx never built.
//   - R8 post-mortem: cost kernel ILP/latency-bound (VGPR 64, all pipes <10%).
//   - R9: single-pass bf16 cost GEMM (error ~0.07 rms ~ fp16-C quantization;
//     24->8 MFMA, 12->6 loads per kc); round kernel register-resident tile
//     (16 loads prefetched, then pure compute) + two-pass col softmin
//     (3->2 exp2/elem); tl (lo-part) buffers deleted.
// ---------------------------------------------------------------------------

typedef __attribute__((ext_vector_type(8))) short short8;
typedef __attribute__((ext_vector_type(4))) float f32x4;
typedef __attribute__((ext_vector_type(8))) unsigned short u16x8;
typedef __attribute__((ext_vector_type(4))) unsigned short u16x4;

#define LOG2E 1.4426950408889634
#define LN2   0.6931471805599453

__device__ __forceinline__ float exp2fast(float x){
#if __has_builtin(__builtin_amdgcn_exp2f)
    return __builtin_amdgcn_exp2f(x);
#else
    return exp2f(x);
#endif
}
__device__ __forceinline__ void lse2_merge(float& m, float& s, float mo, float so){
    float M2 = fmaxf(m, mo);
    s = s * exp2fast(m - M2) + so * exp2fast(mo - M2);
    m = M2;
}
__device__ __forceinline__ unsigned short f2bf(float x){
    unsigned u = __float_as_uint(x);
    unsigned r = u + 0x7fffu + ((u >> 16) & 1u);
    return (unsigned short)(r >> 16);
}
__device__ __forceinline__ float h2f(unsigned short u){
    _Float16 h; __builtin_memcpy(&h, &u, 2); return (float)h;
}
__device__ __forceinline__ unsigned short f2h(float f){
    _Float16 h = (_Float16)f; unsigned short u; __builtin_memcpy(&u, &h, 2); return u;
}
__device__ __forceinline__ float max8(const float* v){
    return fmaxf(fmaxf(fmaxf(v[0], v[1]), fmaxf(v[2], v[3])),
                 fmaxf(fmaxf(v[4], v[5]), fmaxf(v[6], v[7])));
}

// ----------------------------- setup kernels -------------------------------

__global__ void k_transposeW(const float* __restrict__ W, float* __restrict__ WT){
    int b = blockIdx.x, t = threadIdx.x;   // WT[k][o] = W[o][k]
    WT[b * 128 + t] = W[t * 128 + b];
}

__global__ __launch_bounds__(128)
void k_transform_all(const float* __restrict__ d, const float* __restrict__ si,
                     const float* __restrict__ sj, const float* __restrict__ WT,
                     unsigned short* __restrict__ th, float* __restrict__ hn)
{
    __shared__ float xs[8][128];
    __shared__ float red[16];
    const int t = threadIdx.x;
    const int r0 = blockIdx.x * 8;
    const float* src; int sr;
    if (r0 < 4096)      { src = d;  sr = r0; }
    else if (r0 < 6144) { src = si; sr = r0 - 4096; }
    else                { src = sj; sr = r0 - 6144; }
    for (int rr = 0; rr < 8; ++rr)
        xs[rr][t] = src[(size_t)(sr + rr) * 128 + t];
    __syncthreads();
    float acc[8];
#pragma unroll
    for (int rr = 0; rr < 8; ++rr) acc[rr] = 0.f;
    for (int k = 0; k < 128; ++k) {
        float wv = WT[k * 128 + t];
#pragma unroll
        for (int rr = 0; rr < 8; ++rr) acc[rr] = fmaf(xs[rr][k], wv, acc[rr]);
    }
#pragma unroll
    for (int rr = 0; rr < 8; ++rr) {
        float a = acc[rr];
        th[(size_t)(r0 + rr) * 128 + t] = f2bf(a);
        float sq = a * a;
#pragma unroll
        for (int o = 1; o < 64; o <<= 1) sq += __shfl_xor(sq, o);
        if ((t & 63) == 0) red[(t >> 6) * 8 + rr] = sq;
    }
    __syncthreads();
    if (t < 8) hn[r0 + t] = 0.5f * (red[t] + red[8 + t]);
}

__global__ void k_log_all(const float* __restrict__ h, const float* __restrict__ hi,
                          const float* __restrict__ hj, float* __restrict__ lg)
{
    int i = blockIdx.x * 256 + threadIdx.x;   // 8192 total
    float x;
    if (i < 4096)      x = h[i];
    else if (i < 6144) x = hi[i - 4096];
    else               x = hj[i - 6144];
    lg[i] = __log2f(x);
}

// ------------------------------ cost GEMM (MFMA) ---------------------------
// C[i][j] = max(hna[i]+hnb[j]-dot, 0) fp16; single bf16 pass.
// Block 64x128, wave 32x64 (2x4 frags). LDS-staged coalesced epilogue.
struct CostPair {
    const unsigned short *Ah, *Bh;
    const float *hna, *hnb;
    unsigned short* C; int ldc; int nty;
};
struct CostQuad { CostPair p[4]; };

#define CPAD 140

__global__ __launch_bounds__(256)
void k_cost_mfma(CostQuad Q)
{
    CostPair P = Q.p[blockIdx.z];
    if ((int)blockIdx.y >= P.nty) return;
    const int i0 = blockIdx.y * 64, j0 = blockIdx.x * 128;
    const int w = threadIdx.x >> 6, lane = threadIdx.x & 63;
    const int rh = w >> 1, ch = w & 1;
    const int ar = i0 + rh * 32;
    const int bc = j0 + ch * 64;
    const int lrow = lane & 15;
    const int kgrp = (lane >> 4) * 8;

    __shared__ unsigned short lds_c[64][CPAD];

    f32x4 acc[2][4];
#pragma unroll
    for (int a = 0; a < 2; ++a)
#pragma unroll
        for (int c = 0; c < 4; ++c) acc[a][c] = (f32x4){0.f, 0.f, 0.f, 0.f};

    // prefetch all fragments for K=128 (8 + 16 short8 = modest VGPR)
    short8 ah[2][4], bh[4][4];
#pragma unroll
    for (int kc = 0; kc < 4; ++kc) {
#pragma unroll
        for (int f = 0; f < 2; ++f)
            ah[f][kc] = *reinterpret_cast<const short8*>(
                P.Ah + (size_t)(ar + f * 16 + lrow) * 128 + kc * 32 + kgrp);
#pragma unroll
        for (int f = 0; f < 4; ++f)
            bh[f][kc] = *reinterpret_cast<const short8*>(
                P.Bh + (size_t)(bc + f * 16 + lrow) * 128 + kc * 32 + kgrp);
    }
#pragma unroll
    for (int kc = 0; kc < 4; ++kc)
#pragma unroll
        for (int fi = 0; fi < 2; ++fi)
#pragma unroll
            for (int fj = 0; fj < 4; ++fj)
                acc[fi][fj] = __builtin_amdgcn_mfma_f32_16x16x32_bf16(
                    bh[fj][kc], ah[fi][kc], acc[fi][fj], 0, 0, 0);

    // C^T frag -> LDS stage
    const int rloc = lane & 15, cloc = (lane >> 4) * 4;
#pragma unroll
    for (int fi = 0; fi < 2; ++fi) {
        int lr = rh * 32 + fi * 16 + rloc;
        float ha = P.hna[i0 + lr];
#pragma unroll
        for (int fj = 0; fj < 4; ++fj) {
            int lc = ch * 64 + fj * 16 + cloc;
            f32x4 hb = *reinterpret_cast<const f32x4*>(P.hnb + j0 + lc);
            u16x4 v;
#pragma unroll
            for (int e = 0; e < 4; ++e)
                v[e] = f2h(fmaxf(ha + hb[e] - acc[fi][fj][e], 0.f));
            *reinterpret_cast<u16x4*>(&lds_c[lr][lc]) = v;
        }
    }
    __syncthreads();
    // coalesced store: thread t -> row t>>2, 32-col quarter t&3
    {
        const int row = threadIdx.x >> 2, q = threadIdx.x & 3;
        const unsigned short* srcp = &lds_c[row][q * 32];
        unsigned short* dstp = P.C + (size_t)(i0 + row) * P.ldc + j0 + q * 32;
#pragma unroll
        for (int k = 0; k < 4; ++k)
            *reinterpret_cast<u16x8*>(dstp + 8 * k) =
                *reinterpret_cast<const u16x8*>(srcp + 8 * k);
    }
}

// ------------------------------ round kernel -------------------------------
// 16 rows x 2048 cols; thread t owns cols [8t,8t+8). The 16 u16x8 row slices
// are prefetched into registers, then: row pass (max tree + 1 exp2/elem) and
// col pass (per-col 16-row max tree + 1 exp2/elem). f/gb finalized in-kernel;
// col partials go to pm/ps for k_comb3.

struct R4Task {
    const unsigned short* C;
    const float* WB; const float* WA;
    const float* fold; const float* la;
    float* fout; float* fwout;
    float* pm; float* ps;
    int blk0;
};
struct R4YTask {
    const unsigned short* C; const float* Wv;
    const float* fold; const float* logself;
    float* vout; float* wout;
    int blk0;
};
struct R4Args {
    R4Task d[2]; R4YTask y[2];
    float ie2, epsln2, ie2n, alpha, beta;
    int yblk0;
};

__global__ __launch_bounds__(256, 3)
void k_round5(R4Args A)
{
    __shared__ float lmS[16][256];
    __shared__ float lsS[16][256];
    const int b = blockIdx.x;
    const int tid = threadIdx.x;
    const float nie2 = -A.ie2;
    const int c0 = tid * 8;

    float mrow[16], srow[16];
    u16x8 cr[16];

    if (b >= A.yblk0) {
        // ---- yy row-only tile ----
        R4YTask T = (b >= A.y[1].blk0) ? A.y[1] : A.y[0];
        const int chunk = b - T.blk0;
        const int row0 = chunk * 16;
#pragma unroll
        for (int r = 0; r < 16; ++r)
            cr[r] = *reinterpret_cast<const u16x8*>(T.C + (size_t)(row0 + r) * 2048 + c0);
        float wb[8];
#pragma unroll
        for (int e = 0; e < 8; ++e) wb[e] = T.Wv[c0 + e];
#pragma unroll
        for (int r = 0; r < 16; ++r) {
            float v[8];
#pragma unroll
            for (int e = 0; e < 8; ++e) v[e] = fmaf(h2f(cr[r][e]), nie2, wb[e]);
            float M8 = max8(v);
            float s8 = 0.f;
#pragma unroll
            for (int e = 0; e < 8; ++e) s8 += exp2fast(v[e] - M8);
            mrow[r] = M8; srow[r] = s8;
        }
#pragma unroll
        for (int r = 0; r < 16; ++r) { lmS[r][tid] = mrow[r]; lsS[r][tid] = srow[r]; }
        __syncthreads();
        {
            const int row = tid >> 4, g = tid & 15;
            float m = lmS[row][g], s = lsS[row][g];
#pragma unroll
            for (int k = 1; k < 16; ++k)
                lse2_merge(m, s, lmS[row][g + 16 * k], lsS[row][g + 16 * k]);
#pragma unroll
            for (int o = 1; o < 16; o <<= 1) {
                float mo = __shfl_xor(m, o), so = __shfl_xor(s, o);
                lse2_merge(m, s, mo, so);
            }
            if (g == 0) {
                int rr = row0 + row;
                float val  = -A.epsln2 * (m + __log2f(s));
                float vnew = A.alpha * T.fold[rr] + A.beta * val;
                T.vout[rr] = vnew;
                T.wout[rr] = fmaf(vnew, A.ie2n, T.logself[rr]);
            }
        }
        return;
    }

    // ---- dual xy tile ----
    R4Task T = (b >= A.d[1].blk0) ? A.d[1] : A.d[0];
    const int chunk = b - T.blk0;
    const int row0 = chunk * 16;
#pragma unroll
    for (int r = 0; r < 16; ++r)
        cr[r] = *reinterpret_cast<const u16x8*>(T.C + (size_t)(row0 + r) * 2048 + c0);
    float wb[8];
#pragma unroll
    for (int e = 0; e < 8; ++e) wb[e] = T.WB[c0 + e];
    float wa[16];
#pragma unroll
    for (int r = 0; r < 16; ++r) wa[r] = T.WA[row0 + r];

    // row pass
#pragma unroll
    for (int r = 0; r < 16; ++r) {
        float v[8];
#pragma unroll
        for (int e = 0; e < 8; ++e) v[e] = fmaf(h2f(cr[r][e]), nie2, wb[e]);
        float M8 = max8(v);
        float s8 = 0.f;
#pragma unroll
        for (int e = 0; e < 8; ++e) s8 += exp2fast(v[e] - M8);
        mrow[r] = M8; srow[r] = s8;
    }
    // col pass: per column, two-pass over the 16 register-resident rows
    float mcol[8], scol[8];
#pragma unroll
    for (int e = 0; e < 8; ++e) {
        float v[16];
#pragma unroll
        for (int r = 0; r < 16; ++r) v[r] = fmaf(h2f(cr[r][e]), nie2, wa[r]);
        float M = fmaxf(
            fmaxf(fmaxf(fmaxf(v[0], v[1]), fmaxf(v[2], v[3])),
                  fmaxf(fmaxf(v[4], v[5]), fmaxf(v[6], v[7]))),
            fmaxf(fmaxf(fmaxf(v[8], v[9]), fmaxf(v[10], v[11])),
                  fmaxf(fmaxf(v[12], v[13]), fmaxf(v[14], v[15]))));
        float s = 0.f;
#pragma unroll
        for (int r = 0; r < 16; ++r) s += exp2fast(v[r] - M);
        mcol[e] = M; scol[e] = s;
    }
    {
        size_t po = (size_t)chunk * 2048 + c0;
        f32x4 a0 = { mcol[0], mcol[1], mcol[2], mcol[3] };
        f32x4 a1 = { mcol[4], mcol[5], mcol[6], mcol[7] };
        f32x4 b0 = { scol[0], scol[1], scol[2], scol[3] };
        f32x4 b1 = { scol[4], scol[5], scol[6], scol[7] };
        *reinterpret_cast<f32x4*>(T.pm + po)     = a0;
        *reinterpret_cast<f32x4*>(T.pm + po + 4) = a1;
        *reinterpret_cast<f32x4*>(T.ps + po)     = b0;
        *reinterpret_cast<f32x4*>(T.ps + po + 4) = b1;
    }
    // row reduce + f finalize
#pragma unroll
    for (int r = 0; r < 16; ++r) { lmS[r][tid] = mrow[r]; lsS[r][tid] = srow[r]; }
    __syncthreads();
    {
        const int row = tid >> 4, g = tid & 15;
        float m = lmS[row][g], s = lsS[row][g];
#pragma unroll
        for (int k = 1; k < 16; ++k)
            lse2_merge(m, s, lmS[row][g + 16 * k], lsS[row][g + 16 * k]);
#pragma unroll
        for (int o = 1; o < 16; o <<= 1) {
            float mo = __shfl_xor(m, o), so = __shfl_xor(s, o);
            lse2_merge(m, s, mo, so);
        }
        if (g == 0) {
            int rr = row0 + row;
            float val  = -A.epsln2 * (m + __log2f(s));
            float vnew = A.alpha * T.fold[rr] + A.beta * val;
            T.fout[rr] = vnew;
            T.fwout[rr] = fmaf(vnew, A.ie2n, T.la[rr]);
        }
    }
}

// ------------------------------ combine kernel -----------------------------
struct CombA { const float* pm; const float* ps; const float* gold;
               const float* lb; float* gout; float* gwout; };
struct C3Args { CombA a[2]; float epsln2, ie2n, alpha, beta; };

__global__ __launch_bounds__(256)
void k_comb3(C3Args A)
{
    const int b = blockIdx.x;             // 128 blocks: 64 per task
    const int tid = threadIdx.x;
    const int lane = tid & 63, w = tid >> 6;
    CombA T = A.a[b >> 6];
    const int bb = b & 63;
    const int jl = tid & 31, cg = tid >> 5;      // 8 chunk groups
    const int j = bb * 32 + jl;
    float m = -INFINITY, s = 0.f;
    for (int c = cg; c < 256; c += 8)
        lse2_merge(m, s, T.pm[(size_t)c * 2048 + j], T.ps[(size_t)c * 2048 + j]);
    {
        float mo = __shfl_xor(m, 32), so = __shfl_xor(s, 32);
        lse2_merge(m, s, mo, so);
    }
    __shared__ float smm[4][32], sss[4][32];
    if (lane < 32) { smm[w][lane] = m; sss[w][lane] = s; }
    __syncthreads();
    if (tid < 32) {
        m = smm[0][tid]; s = sss[0][tid];
        for (int q = 1; q < 4; ++q) lse2_merge(m, s, smm[q][tid], sss[q][tid]);
        float val = -A.epsln2 * (m + __log2f(s));
        float gnew = A.alpha * T.gold[j] + A.beta * val;
        T.gout[j] = gnew;
        T.gwout[j] = fmaf(gnew, A.ie2n, T.lb[j]);
    }
}

// ------------------------------ final reduce -------------------------------
__global__ __launch_bounds__(1024)
void k_final(const float* __restrict__ h, const float* __restrict__ hi,
             const float* __restrict__ hj,
             const float* __restrict__ f1f, const float* __restrict__ f2f,
             const float* __restrict__ g1f, const float* __restrict__ gb1f,
             const float* __restrict__ g2f, const float* __restrict__ gb2f,
             int N, int M, float* __restrict__ out)
{
    float acc = 0.f;
    for (int i = threadIdx.x; i < N; i += 1024)
        acc += h[i] * (f2f[i] - f1f[i]);
    for (int j = threadIdx.x; j < M; j += 1024)
        acc += hj[j] * (g2f[j] - gb2f[j]) - hi[j] * (g1f[j] - gb1f[j]);
#pragma unroll
    for (int o = 32; o; o >>= 1) acc += __shfl_xor(acc, o);
    __shared__ float red[16];
    const int lane = threadIdx.x & 63, w = threadIdx.x >> 6;
    if (lane == 0) red[w] = acc;
    __syncthreads();
    if (threadIdx.x == 0) {
        float t = 0.f;
        for (int q = 0; q < 16; ++q) t += red[q];
        out[0] = 1.f / (1.f + expf(-t));   // SCALING_FACTOR = 1
    }
}

// ------------------------------ orchestration ------------------------------

extern "C" void kernel_launch(void* const* d_in, const int* in_sizes, int n_in,
                              void* d_out, int out_size, void* d_ws, size_t ws_size,
                              hipStream_t stream)
{
    const float* d  = (const float*)d_in[0];
    const float* si = (const float*)d_in[1];
    const float* sj = (const float*)d_in[2];
    const float* h  = (const float*)d_in[3];
    const float* hi = (const float*)d_in[4];
    const float* hj = (const float*)d_in[5];
    const float* W  = (const float*)d_in[6];
    float* out = (float*)d_out;

    const int N = 4096, M = 2048;
    (void)in_sizes; (void)n_in; (void)out_size; (void)ws_size;

    float* ws = (float*)d_ws;
    size_t off = 0;
    auto alloc = [&](size_t n) { float* p = ws + off; off += (n + 63) & ~(size_t)63; return p; };

    float* WT    = alloc(128 * 128);
    float* lg2   = alloc(8192);
    float* hnAll = alloc(8192);
    unsigned short* thAll = (unsigned short*)alloc(8192 * 128 / 2);
    float* f1[2]  = { alloc(N), alloc(N) };
    float* f2[2]  = { alloc(N), alloc(N) };
    float* g1[2]  = { alloc(M), alloc(M) };
    float* g2[2]  = { alloc(M), alloc(M) };
    float* gb1[2] = { alloc(M), alloc(M) };
    float* gb2[2] = { alloc(M), alloc(M) };
    float* WA1[2] = { alloc(N), alloc(N) };
    float* WA2[2] = { alloc(N), alloc(N) };
    float* WB1[2] = { alloc(M), alloc(M) };
    float* WB2[2] = { alloc(M), alloc(M) };
    float* WY1[2] = { alloc(M), alloc(M) };
    float* WY2[2] = { alloc(M), alloc(M) };
    float* f1f = alloc(N); float* f2f = alloc(N);
    float* g1f = alloc(M); float* g2f = alloc(M);
    float* gb1f = alloc(M); float* gb2f = alloc(M);
    unsigned short* C1  = (unsigned short*)alloc((size_t)N * M / 2);
    unsigned short* C2  = (unsigned short*)alloc((size_t)N * M / 2);
    unsigned short* Cy1 = (unsigned short*)alloc((size_t)M * M / 2);
    unsigned short* Cy2 = (unsigned short*)alloc((size_t)M * M / 2);
    float* pm1 = alloc((size_t)256 * 2048);
    float* ps1 = alloc((size_t)256 * 2048);
    float* pm2 = alloc((size_t)256 * 2048);
    float* ps2 = alloc((size_t)256 * 2048);

    float* la2  = lg2;
    float* lbi2 = lg2 + 4096;
    float* lbj2 = lg2 + 6144;
    const float* hnx = hnAll;
    const float* hni = hnAll + 4096;
    const float* hnj = hnAll + 6144;
    const unsigned short* tdh  = thAll;
    const unsigned short* tsih = thAll + (size_t)4096 * 128;
    const unsigned short* tsjh = thAll + (size_t)6144 * 128;

    // ---- setup ----
    k_transposeW<<<128, 128, 0, stream>>>(W, WT);
    k_transform_all<<<1024, 128, 0, stream>>>(d, si, sj, WT, thAll, hnAll);
    k_log_all<<<32, 256, 0, stream>>>(h, hi, hj, lg2);

    // ---- cost matrices: 4 GEMMs in one launch (64x128 block tiles) ----
    CostQuad Q;
    Q.p[0] = { tdh,  tsih, hnx, hni, C1,  M, 64 };
    Q.p[1] = { tdh,  tsjh, hnx, hnj, C2,  M, 64 };
    Q.p[2] = { tsih, tsih, hni, hni, Cy1, M, 32 };
    Q.p[3] = { tsjh, tsjh, hnj, hnj, Cy2, M, 32 };
    k_cost_mfma<<<dim3(M / 128, N / 64, 4), 256, 0, stream>>>(Q);

    // ---- eps schedule ----
    double epsl[16]; int ne = 0;
    for (double sg = 32.0; sg > 0.05; sg *= 0.5) epsl[ne++] = sg * sg;
    epsl[ne++] = 0.05 * 0.05;   // ne == 11

    for (int r = 0; r <= ne + 1; ++r) {
        const bool init = (r == 0), fin = (r == ne + 1);
        const double eps  = init ? epsl[0] : (fin ? epsl[ne - 1] : epsl[r - 1]);
        const double epsn = (r + 1 <= ne) ? epsl[r] : epsl[ne - 1];
        const int in = init ? 0 : (r - 1) & 1;
        const int o  = r & 1;

        R4Args RA;
        RA.ie2    = (float)(LOG2E / eps);
        RA.epsln2 = (float)(eps * LN2);
        RA.ie2n   = (float)(LOG2E / epsn);
        RA.alpha  = (init || fin) ? 0.0f : 0.5f;
        RA.beta   = (init || fin) ? 1.0f : 0.5f;
        RA.yblk0  = 512;
        RA.d[0] = { C1, init ? lbi2 : WB1[in], init ? la2 : WA1[in], f1[in], la2,
                    fin ? f1f : f1[o], WA1[o], pm1, ps1, 0 };
        RA.d[1] = { C2, init ? lbj2 : WB2[in], init ? la2 : WA2[in], f2[in], la2,
                    fin ? f2f : f2[o], WA2[o], pm2, ps2, 256 };
        RA.y[0] = { Cy1, init ? lbi2 : WY1[in], gb1[in], lbi2,
                    fin ? gb1f : gb1[o], WY1[o], 512 };
        RA.y[1] = { Cy2, init ? lbj2 : WY2[in], gb2[in], lbj2,
                    fin ? gb2f : gb2[o], WY2[o], 640 };
        k_round5<<<768, 256, 0, stream>>>(RA);

        C3Args CA;
        CA.epsln2 = (float)(eps * LN2);
        CA.ie2n   = (float)(LOG2E / epsn);
        CA.alpha  = RA.alpha;
        CA.beta   = RA.beta;
        CA.a[0] = { pm1, ps1, g1[in], lbi2, fin ? g1f : g1[o], WB1[o] };
        CA.a[1] = { pm2, ps2, g2[in], lbj2, fin ? g2f : g2[o], WB2[o] };
        k_comb3<<<128, 256, 0, stream>>>(CA);
    }

    k_final<<<1, 1024, 0, stream>>>(h, hi, hj, f1f, f2f, g1f, gb1f, g2f, gb2f, N, M, out);
}

// Round 10
// 363.722 us; speedup vs baseline: 1.2718x; 1.1487x over previous
//
#include <hip/hip_runtime.h>
#include <math.h>

// ---------------------------------------------------------------------------
// LinSinkhornPRModel: sigmoid(dist2 - dist1) of two Sinkhorn divergences.
//   - f_aa self-term cancels in dist2-dist1 -> C_xx never built.
//   - R9: single-pass bf16 cost GEMM; register-resident round tile (418us).
//   - R10: k_comb 128->512 blocks (was 0.5 block/CU starved); cost GEMM as 4
//     exact-grid dispatches (no idle blocks + rocprof visibility for rounds).
// ---------------------------------------------------------------------------

typedef __attribute__((ext_vector_type(8))) short short8;
typedef __attribute__((ext_vector_type(4))) float f32x4;
typedef __attribute__((ext_vector_type(8))) unsigned short u16x8;
typedef __attribute__((ext_vector_type(4))) unsigned short u16x4;

#define LOG2E 1.4426950408889634
#define LN2   0.6931471805599453

__device__ __forceinline__ float exp2fast(float x){
#if __has_builtin(__builtin_amdgcn_exp2f)
    return __builtin_amdgcn_exp2f(x);
#else
    return exp2f(x);
#endif
}
__device__ __forceinline__ void lse2_merge(float& m, float& s, float mo, float so){
    float M2 = fmaxf(m, mo);
    s = s * exp2fast(m - M2) + so * exp2fast(mo - M2);
    m = M2;
}
__device__ __forceinline__ unsigned short f2bf(float x){
    unsigned u = __float_as_uint(x);
    unsigned r = u + 0x7fffu + ((u >> 16) & 1u);
    return (unsigned short)(r >> 16);
}
__device__ __forceinline__ float h2f(unsigned short u){
    _Float16 h; __builtin_memcpy(&h, &u, 2); return (float)h;
}
__device__ __forceinline__ unsigned short f2h(float f){
    _Float16 h = (_Float16)f; unsigned short u; __builtin_memcpy(&u, &h, 2); return u;
}
__device__ __forceinline__ float max8(const float* v){
    return fmaxf(fmaxf(fmaxf(v[0], v[1]), fmaxf(v[2], v[3])),
                 fmaxf(fmaxf(v[4], v[5]), fmaxf(v[6], v[7])));
}

// ----------------------------- setup kernels -------------------------------

__global__ void k_transposeW(const float* __restrict__ W, float* __restrict__ WT){
    int b = blockIdx.x, t = threadIdx.x;   // WT[k][o] = W[o][k]
    WT[b * 128 + t] = W[t * 128 + b];
}

__global__ __launch_bounds__(128)
void k_transform_all(const float* __restrict__ d, const float* __restrict__ si,
                     const float* __restrict__ sj, const float* __restrict__ WT,
                     unsigned short* __restrict__ th, float* __restrict__ hn)
{
    __shared__ float xs[8][128];
    __shared__ float red[16];
    const int t = threadIdx.x;
    const int r0 = blockIdx.x * 8;
    const float* src; int sr;
    if (r0 < 4096)      { src = d;  sr = r0; }
    else if (r0 < 6144) { src = si; sr = r0 - 4096; }
    else                { src = sj; sr = r0 - 6144; }
    for (int rr = 0; rr < 8; ++rr)
        xs[rr][t] = src[(size_t)(sr + rr) * 128 + t];
    __syncthreads();
    float acc[8];
#pragma unroll
    for (int rr = 0; rr < 8; ++rr) acc[rr] = 0.f;
    for (int k = 0; k < 128; ++k) {
        float wv = WT[k * 128 + t];
#pragma unroll
        for (int rr = 0; rr < 8; ++rr) acc[rr] = fmaf(xs[rr][k], wv, acc[rr]);
    }
#pragma unroll
    for (int rr = 0; rr < 8; ++rr) {
        float a = acc[rr];
        th[(size_t)(r0 + rr) * 128 + t] = f2bf(a);
        float sq = a * a;
#pragma unroll
        for (int o = 1; o < 64; o <<= 1) sq += __shfl_xor(sq, o);
        if ((t & 63) == 0) red[(t >> 6) * 8 + rr] = sq;
    }
    __syncthreads();
    if (t < 8) hn[r0 + t] = 0.5f * (red[t] + red[8 + t]);
}

__global__ void k_log_all(const float* __restrict__ h, const float* __restrict__ hi,
                          const float* __restrict__ hj, float* __restrict__ lg)
{
    int i = blockIdx.x * 256 + threadIdx.x;   // 8192 total
    float x;
    if (i < 4096)      x = h[i];
    else if (i < 6144) x = hi[i - 4096];
    else               x = hj[i - 6144];
    lg[i] = __log2f(x);
}

// ------------------------------ cost GEMM (MFMA) ---------------------------
// C[i][j] = max(hna[i]+hnb[j]-dot, 0) fp16; single bf16 pass.
// Block 64x128, wave 32x64 (2x4 frags). LDS-staged coalesced epilogue.
// One dispatch per matrix, exact grid dim3(cols/128, rows/64).
struct CostPair {
    const unsigned short *Ah, *Bh;
    const float *hna, *hnb;
    unsigned short* C; int ldc;
};

#define CPAD 140

__global__ __launch_bounds__(256)
void k_cost_mfma(CostPair P)
{
    const int i0 = blockIdx.y * 64, j0 = blockIdx.x * 128;
    const int w = threadIdx.x >> 6, lane = threadIdx.x & 63;
    const int rh = w >> 1, ch = w & 1;
    const int ar = i0 + rh * 32;
    const int bc = j0 + ch * 64;
    const int lrow = lane & 15;
    const int kgrp = (lane >> 4) * 8;

    __shared__ unsigned short lds_c[64][CPAD];

    f32x4 acc[2][4];
#pragma unroll
    for (int a = 0; a < 2; ++a)
#pragma unroll
        for (int c = 0; c < 4; ++c) acc[a][c] = (f32x4){0.f, 0.f, 0.f, 0.f};

    short8 ah[2][4], bh[4][4];
#pragma unroll
    for (int kc = 0; kc < 4; ++kc) {
#pragma unroll
        for (int f = 0; f < 2; ++f)
            ah[f][kc] = *reinterpret_cast<const short8*>(
                P.Ah + (size_t)(ar + f * 16 + lrow) * 128 + kc * 32 + kgrp);
#pragma unroll
        for (int f = 0; f < 4; ++f)
            bh[f][kc] = *reinterpret_cast<const short8*>(
                P.Bh + (size_t)(bc + f * 16 + lrow) * 128 + kc * 32 + kgrp);
    }
#pragma unroll
    for (int kc = 0; kc < 4; ++kc)
#pragma unroll
        for (int fi = 0; fi < 2; ++fi)
#pragma unroll
            for (int fj = 0; fj < 4; ++fj)
                acc[fi][fj] = __builtin_amdgcn_mfma_f32_16x16x32_bf16(
                    bh[fj][kc], ah[fi][kc], acc[fi][fj], 0, 0, 0);

    // C^T frag -> LDS stage
    const int rloc = lane & 15, cloc = (lane >> 4) * 4;
#pragma unroll
    for (int fi = 0; fi < 2; ++fi) {
        int lr = rh * 32 + fi * 16 + rloc;
        float ha = P.hna[i0 + lr];
#pragma unroll
        for (int fj = 0; fj < 4; ++fj) {
            int lc = ch * 64 + fj * 16 + cloc;
            f32x4 hb = *reinterpret_cast<const f32x4*>(P.hnb + j0 + lc);
            u16x4 v;
#pragma unroll
            for (int e = 0; e < 4; ++e)
                v[e] = f2h(fmaxf(ha + hb[e] - acc[fi][fj][e], 0.f));
            *reinterpret_cast<u16x4*>(&lds_c[lr][lc]) = v;
        }
    }
    __syncthreads();
    // coalesced store: thread t -> row t>>2, 32-col quarter t&3
    {
        const int row = threadIdx.x >> 2, q = threadIdx.x & 3;
        const unsigned short* srcp = &lds_c[row][q * 32];
        unsigned short* dstp = P.C + (size_t)(i0 + row) * P.ldc + j0 + q * 32;
#pragma unroll
        for (int k = 0; k < 4; ++k)
            *reinterpret_cast<u16x8*>(dstp + 8 * k) =
                *reinterpret_cast<const u16x8*>(srcp + 8 * k);
    }
}

// ------------------------------ round kernel -------------------------------
// 16 rows x 2048 cols; thread t owns cols [8t,8t+8). 16 u16x8 row slices
// prefetched into registers; row pass (max tree + 1 exp2/elem); col pass
// (per-col 16-row max tree + 1 exp2/elem). f/gb finalized in-kernel.

struct R4Task {
    const unsigned short* C;
    const float* WB; const float* WA;
    const float* fold; const float* la;
    float* fout; float* fwout;
    float* pm; float* ps;
    int blk0;
};
struct R4YTask {
    const unsigned short* C; const float* Wv;
    const float* fold; const float* logself;
    float* vout; float* wout;
    int blk0;
};
struct R4Args {
    R4Task d[2]; R4YTask y[2];
    float ie2, epsln2, ie2n, alpha, beta;
    int yblk0;
};

__global__ __launch_bounds__(256, 3)
void k_round5(R4Args A)
{
    __shared__ float lmS[16][256];
    __shared__ float lsS[16][256];
    const int b = blockIdx.x;
    const int tid = threadIdx.x;
    const float nie2 = -A.ie2;
    const int c0 = tid * 8;

    float mrow[16], srow[16];
    u16x8 cr[16];

    if (b >= A.yblk0) {
        // ---- yy row-only tile ----
        R4YTask T = (b >= A.y[1].blk0) ? A.y[1] : A.y[0];
        const int chunk = b - T.blk0;
        const int row0 = chunk * 16;
#pragma unroll
        for (int r = 0; r < 16; ++r)
            cr[r] = *reinterpret_cast<const u16x8*>(T.C + (size_t)(row0 + r) * 2048 + c0);
        float wb[8];
#pragma unroll
        for (int e = 0; e < 8; ++e) wb[e] = T.Wv[c0 + e];
#pragma unroll
        for (int r = 0; r < 16; ++r) {
            float v[8];
#pragma unroll
            for (int e = 0; e < 8; ++e) v[e] = fmaf(h2f(cr[r][e]), nie2, wb[e]);
            float M8 = max8(v);
            float s8 = 0.f;
#pragma unroll
            for (int e = 0; e < 8; ++e) s8 += exp2fast(v[e] - M8);
            mrow[r] = M8; srow[r] = s8;
        }
#pragma unroll
        for (int r = 0; r < 16; ++r) { lmS[r][tid] = mrow[r]; lsS[r][tid] = srow[r]; }
        __syncthreads();
        {
            const int row = tid >> 4, g = tid & 15;
            float m = lmS[row][g], s = lsS[row][g];
#pragma unroll
            for (int k = 1; k < 16; ++k)
                lse2_merge(m, s, lmS[row][g + 16 * k], lsS[row][g + 16 * k]);
#pragma unroll
            for (int o = 1; o < 16; o <<= 1) {
                float mo = __shfl_xor(m, o), so = __shfl_xor(s, o);
                lse2_merge(m, s, mo, so);
            }
            if (g == 0) {
                int rr = row0 + row;
                float val  = -A.epsln2 * (m + __log2f(s));
                float vnew = A.alpha * T.fold[rr] + A.beta * val;
                T.vout[rr] = vnew;
                T.wout[rr] = fmaf(vnew, A.ie2n, T.logself[rr]);
            }
        }
        return;
    }

    // ---- dual xy tile ----
    R4Task T = (b >= A.d[1].blk0) ? A.d[1] : A.d[0];
    const int chunk = b - T.blk0;
    const int row0 = chunk * 16;
#pragma unroll
    for (int r = 0; r < 16; ++r)
        cr[r] = *reinterpret_cast<const u16x8*>(T.C + (size_t)(row0 + r) * 2048 + c0);
    float wb[8];
#pragma unroll
    for (int e = 0; e < 8; ++e) wb[e] = T.WB[c0 + e];
    float wa[16];
#pragma unroll
    for (int r = 0; r < 16; ++r) wa[r] = T.WA[row0 + r];

    // row pass
#pragma unroll
    for (int r = 0; r < 16; ++r) {
        float v[8];
#pragma unroll
        for (int e = 0; e < 8; ++e) v[e] = fmaf(h2f(cr[r][e]), nie2, wb[e]);
        float M8 = max8(v);
        float s8 = 0.f;
#pragma unroll
        for (int e = 0; e < 8; ++e) s8 += exp2fast(v[e] - M8);
        mrow[r] = M8; srow[r] = s8;
    }
    // col pass: per column, two-pass over the 16 register-resident rows
    float mcol[8], scol[8];
#pragma unroll
    for (int e = 0; e < 8; ++e) {
        float v[16];
#pragma unroll
        for (int r = 0; r < 16; ++r) v[r] = fmaf(h2f(cr[r][e]), nie2, wa[r]);
        float M = fmaxf(
            fmaxf(fmaxf(fmaxf(v[0], v[1]), fmaxf(v[2], v[3])),
                  fmaxf(fmaxf(v[4], v[5]), fmaxf(v[6], v[7]))),
            fmaxf(fmaxf(fmaxf(v[8], v[9]), fmaxf(v[10], v[11])),
                  fmaxf(fmaxf(v[12], v[13]), fmaxf(v[14], v[15]))));
        float s = 0.f;
#pragma unroll
        for (int r = 0; r < 16; ++r) s += exp2fast(v[r] - M);
        mcol[e] = M; scol[e] = s;
    }
    {
        size_t po = (size_t)chunk * 2048 + c0;
        f32x4 a0 = { mcol[0], mcol[1], mcol[2], mcol[3] };
        f32x4 a1 = { mcol[4], mcol[5], mcol[6], mcol[7] };
        f32x4 b0 = { scol[0], scol[1], scol[2], scol[3] };
        f32x4 b1 = { scol[4], scol[5], scol[6], scol[7] };
        *reinterpret_cast<f32x4*>(T.pm + po)     = a0;
        *reinterpret_cast<f32x4*>(T.pm + po + 4) = a1;
        *reinterpret_cast<f32x4*>(T.ps + po)     = b0;
        *reinterpret_cast<f32x4*>(T.ps + po + 4) = b1;
    }
    // row reduce + f finalize
#pragma unroll
    for (int r = 0; r < 16; ++r) { lmS[r][tid] = mrow[r]; lsS[r][tid] = srow[r]; }
    __syncthreads();
    {
        const int row = tid >> 4, g = tid & 15;
        float m = lmS[row][g], s = lsS[row][g];
#pragma unroll
        for (int k = 1; k < 16; ++k)
            lse2_merge(m, s, lmS[row][g + 16 * k], lsS[row][g + 16 * k]);
#pragma unroll
        for (int o = 1; o < 16; o <<= 1) {
            float mo = __shfl_xor(m, o), so = __shfl_xor(s, o);
            lse2_merge(m, s, mo, so);
        }
        if (g == 0) {
            int rr = row0 + row;
            float val  = -A.epsln2 * (m + __log2f(s));
            float vnew = A.alpha * T.fold[rr] + A.beta * val;
            T.fout[rr] = vnew;
            T.fwout[rr] = fmaf(vnew, A.ie2n, T.la[rr]);
        }
    }
}

// ------------------------------ combine kernel -----------------------------
// 512 blocks: 8 columns x 32 threads/col. Thread (jl=tid&7, cg=tid>>3) merges
// chunks {cg, cg+32, ...} (8 serial); 3-level shfl butterfly (masks 8/16/32)
// merges the wave's 8 cg-slices; LDS merges the 4 waves.
struct CombA { const float* pm; const float* ps; const float* gold;
               const float* lb; float* gout; float* gwout; };
struct C3Args { CombA a[2]; float epsln2, ie2n, alpha, beta; };

__global__ __launch_bounds__(256)
void k_comb4(C3Args A)
{
    const int b = blockIdx.x;             // 512 blocks: 256 per task
    const int tid = threadIdx.x;
    const int lane = tid & 63, w = tid >> 6;
    CombA T = A.a[b >> 8];
    const int jl = tid & 7;
    const int j = (b & 255) * 8 + jl;
    const int cg = tid >> 3;              // 0..31
    float m = -INFINITY, s = 0.f;
#pragma unroll
    for (int k = 0; k < 8; ++k) {
        int c = cg + 32 * k;
        lse2_merge(m, s, T.pm[(size_t)c * 2048 + j], T.ps[(size_t)c * 2048 + j]);
    }
#pragma unroll
    for (int o = 8; o <= 32; o <<= 1) {
        float mo = __shfl_xor(m, o), so = __shfl_xor(s, o);
        lse2_merge(m, s, mo, so);
    }
    __shared__ float smm[4][8], sss[4][8];
    if (lane < 8) { smm[w][lane] = m; sss[w][lane] = s; }
    __syncthreads();
    if (tid < 8) {
        m = smm[0][tid]; s = sss[0][tid];
#pragma unroll
        for (int q = 1; q < 4; ++q) lse2_merge(m, s, smm[q][tid], sss[q][tid]);
        int jj = (b & 255) * 8 + tid;
        float val = -A.epsln2 * (m + __log2f(s));
        float gnew = A.alpha * T.gold[jj] + A.beta * val;
        T.gout[jj] = gnew;
        T.gwout[jj] = fmaf(gnew, A.ie2n, T.lb[jj]);
    }
}

// ------------------------------ final reduce -------------------------------
__global__ __launch_bounds__(1024)
void k_final(const float* __restrict__ h, const float* __restrict__ hi,
             const float* __restrict__ hj,
             const float* __restrict__ f1f, const float* __restrict__ f2f,
             const float* __restrict__ g1f, const float* __restrict__ gb1f,
             const float* __restrict__ g2f, const float* __restrict__ gb2f,
             int N, int M, float* __restrict__ out)
{
    float acc = 0.f;
    for (int i = threadIdx.x; i < N; i += 1024)
        acc += h[i] * (f2f[i] - f1f[i]);
    for (int j = threadIdx.x; j < M; j += 1024)
        acc += hj[j] * (g2f[j] - gb2f[j]) - hi[j] * (g1f[j] - gb1f[j]);
#pragma unroll
    for (int o = 32; o; o >>= 1) acc += __shfl_xor(acc, o);
    __shared__ float red[16];
    const int lane = threadIdx.x & 63, w = threadIdx.x >> 6;
    if (lane == 0) red[w] = acc;
    __syncthreads();
    if (threadIdx.x == 0) {
        float t = 0.f;
        for (int q = 0; q < 16; ++q) t += red[q];
        out[0] = 1.f / (1.f + expf(-t));   // SCALING_FACTOR = 1
    }
}

// ------------------------------ orchestration ------------------------------

extern "C" void kernel_launch(void* const* d_in, const int* in_sizes, int n_in,
                              void* d_out, int out_size, void* d_ws, size_t ws_size,
                              hipStream_t stream)
{
    const float* d  = (const float*)d_in[0];
    const float* si = (const float*)d_in[1];
    const float* sj = (const float*)d_in[2];
    const float* h  = (const float*)d_in[3];
    const float* hi = (const float*)d_in[4];
    const float* hj = (const float*)d_in[5];
    const float* W  = (const float*)d_in[6];
    float* out = (float*)d_out;

    const int N = 4096, M = 2048;
    (void)in_sizes; (void)n_in; (void)out_size; (void)ws_size;

    float* ws = (float*)d_ws;
    size_t off = 0;
    auto alloc = [&](size_t n) { float* p = ws + off; off += (n + 63) & ~(size_t)63; return p; };

    float* WT    = alloc(128 * 128);
    float* lg2   = alloc(8192);
    float* hnAll = alloc(8192);
    unsigned short* thAll = (unsigned short*)alloc(8192 * 128 / 2);
    float* f1[2]  = { alloc(N), alloc(N) };
    float* f2[2]  = { alloc(N), alloc(N) };
    float* g1[2]  = { alloc(M), alloc(M) };
    float* g2[2]  = { alloc(M), alloc(M) };
    float* gb1[2] = { alloc(M), alloc(M) };
    float* gb2[2] = { alloc(M), alloc(M) };
    float* WA1[2] = { alloc(N), alloc(N) };
    float* WA2[2] = { alloc(N), alloc(N) };
    float* WB1[2] = { alloc(M), alloc(M) };
    float* WB2[2] = { alloc(M), alloc(M) };
    float* WY1[2] = { alloc(M), alloc(M) };
    float* WY2[2] = { alloc(M), alloc(M) };
    float* f1f = alloc(N); float* f2f = alloc(N);
    float* g1f = alloc(M); float* g2f = alloc(M);
    float* gb1f = alloc(M); float* gb2f = alloc(M);
    unsigned short* C1  = (unsigned short*)alloc((size_t)N * M / 2);
    unsigned short* C2  = (unsigned short*)alloc((size_t)N * M / 2);
    unsigned short* Cy1 = (unsigned short*)alloc((size_t)M * M / 2);
    unsigned short* Cy2 = (unsigned short*)alloc((size_t)M * M / 2);
    float* pm1 = alloc((size_t)256 * 2048);
    float* ps1 = alloc((size_t)256 * 2048);
    float* pm2 = alloc((size_t)256 * 2048);
    float* ps2 = alloc((size_t)256 * 2048);

    float* la2  = lg2;
    float* lbi2 = lg2 + 4096;
    float* lbj2 = lg2 + 6144;
    const float* hnx = hnAll;
    const float* hni = hnAll + 4096;
    const float* hnj = hnAll + 6144;
    const unsigned short* tdh  = thAll;
    const unsigned short* tsih = thAll + (size_t)4096 * 128;
    const unsigned short* tsjh = thAll + (size_t)6144 * 128;

    // ---- setup ----
    k_transposeW<<<128, 128, 0, stream>>>(W, WT);
    k_transform_all<<<1024, 128, 0, stream>>>(d, si, sj, WT, thAll, hnAll);
    k_log_all<<<32, 256, 0, stream>>>(h, hi, hj, lg2);

    // ---- cost matrices: 4 exact-grid dispatches ----
    CostPair cp0 = { tdh,  tsih, hnx, hni, C1,  M };
    CostPair cp1 = { tdh,  tsjh, hnx, hnj, C2,  M };
    CostPair cp2 = { tsih, tsih, hni, hni, Cy1, M };
    CostPair cp3 = { tsjh, tsjh, hnj, hnj, Cy2, M };
    k_cost_mfma<<<dim3(M / 128, N / 64), 256, 0, stream>>>(cp0);
    k_cost_mfma<<<dim3(M / 128, N / 64), 256, 0, stream>>>(cp1);
    k_cost_mfma<<<dim3(M / 128, M / 64), 256, 0, stream>>>(cp2);
    k_cost_mfma<<<dim3(M / 128, M / 64), 256, 0, stream>>>(cp3);

    // ---- eps schedule ----
    double epsl[16]; int ne = 0;
    for (double sg = 32.0; sg > 0.05; sg *= 0.5) epsl[ne++] = sg * sg;
    epsl[ne++] = 0.05 * 0.05;   // ne == 11

    for (int r = 0; r <= ne + 1; ++r) {
        const bool init = (r == 0), fin = (r == ne + 1);
        const double eps  = init ? epsl[0] : (fin ? epsl[ne - 1] : epsl[r - 1]);
        const double epsn = (r + 1 <= ne) ? epsl[r] : epsl[ne - 1];
        const int in = init ? 0 : (r - 1) & 1;
        const int o  = r & 1;

        R4Args RA;
        RA.ie2    = (float)(LOG2E / eps);
        RA.epsln2 = (float)(eps * LN2);
        RA.ie2n   = (float)(LOG2E / epsn);
        RA.alpha  = (init || fin) ? 0.0f : 0.5f;
        RA.beta   = (init || fin) ? 1.0f : 0.5f;
        RA.yblk0  = 512;
        RA.d[0] = { C1, init ? lbi2 : WB1[in], init ? la2 : WA1[in], f1[in], la2,
                    fin ? f1f : f1[o], WA1[o], pm1, ps1, 0 };
        RA.d[1] = { C2, init ? lbj2 : WB2[in], init ? la2 : WA2[in], f2[in], la2,
                    fin ? f2f : f2[o], WA2[o], pm2, ps2, 256 };
        RA.y[0] = { Cy1, init ? lbi2 : WY1[in], gb1[in], lbi2,
                    fin ? gb1f : gb1[o], WY1[o], 512 };
        RA.y[1] = { Cy2, init ? lbj2 : WY2[in], gb2[in], lbj2,
                    fin ? gb2f : gb2[o], WY2[o], 640 };
        k_round5<<<768, 256, 0, stream>>>(RA);

        C3Args CA;
        CA.epsln2 = (float)(eps * LN2);
        CA.ie2n   = (float)(LOG2E / epsn);
        CA.alpha  = RA.alpha;
        CA.beta   = RA.beta;
        CA.a[0] = { pm1, ps1, g1[in], lbi2, fin ? g1f : g1[o], WB1[o] };
        CA.a[1] = { pm2, ps2, g2[in], lbj2, fin ? g2f : g2[o], WB2[o] };
        k_comb4<<<512, 256, 0, stream>>>(CA);
    }

    k_final<<<1, 1024, 0, stream>>>(h, hi, hj, f1f, f2f, g1f, gb1f, g2f, gb2f, N, M, out);
}